// Round 10
// baseline (90.967 us; speedup 1.0000x reference)
//
#include <hip/hip_runtime.h>
#include <stdint.h>

// Expansion + checkerboard-preserving dropout.
// Phase 1: pack FINAL mask bits ((rand>0.25 | center) & in-bounds) into 3200 u32.
// Phase 2: fill-shaped main kernel: 256-thread blocks, each block = 16 contiguous
//          output rows (20 KB). Block id is XCD-chunked (bijective: 20480=8*2560)
//          so each XCD owns a contiguous 52 MB output range + a 2.1 MB L2-resident
//          x slice. Stage 8 x rows + 160 mask words via global_load_lds; 5 float4
//          stores per thread.

#define KEEP_SCALE (1.0f / 0.75f)

typedef float f32x4 __attribute__((ext_vector_type(4)));

__global__ __launch_bounds__(256) void build_mask_kernel(
    const float* __restrict__ rv,       // (320,320)
    uint32_t* __restrict__ mask)        // 3200 words, 10 per row
{
    int w = blockIdx.x * 256 + threadIdx.x;
    if (w >= 3200) return;
    int oh  = w / 10;
    int ow0 = (w - oh * 10) * 32;
    int qh = oh / 5, rh = oh - qh * 5;
    int ih = qh + rh - 2;
    bool hok = ((unsigned)ih < 64u);
    bool hc  = (rh == 2);
    const float* rp = rv + oh * 320 + ow0;
    uint32_t m = 0;
    #pragma unroll
    for (int b = 0; b < 32; ++b) {
        int ow = ow0 + b;
        int q = ow / 5, r = ow - q * 5;
        int iw = q + r - 2;
        bool keep = ((rp[b] > 0.25f) || (hc && (r == 2)))
                    && hok && ((unsigned)iw < 64u);
        m |= (uint32_t)keep << b;
    }
    mask[w] = m;
}

__global__ __launch_bounds__(256) void expand_cps_dropout_kernel(
    const float* __restrict__ x,        // (1024, 64, 64)
    const uint32_t* __restrict__ mask,  // 3200 words (bounds folded in)
    float* __restrict__ out)            // (1024, 320, 320)
{
    __shared__ __align__(16) float    xs[8 * 64];   // 2048 B: rows [s0, s0+8)
    __shared__ __align__(16) uint32_t ms[160];      // 640 B: 16 rows x 10 words

    const int t  = threadIdx.x;         // 0..255
    // Bijective XCD chunking: consecutive work on ONE XCD (20480 = 8 * 2560).
    const int b  = ((blockIdx.x & 7) * 2560) + (blockIdx.x >> 3);
    const int bc = b / 20;              // image
    const int rg = b - bc * 20;         // 16-row chunk within image

    const int a = 16 * rg;              // first output row of this block
    int s0 = a / 5 - 2;                 // first staged source row
    s0 = s0 < 0 ? 0 : (s0 > 56 ? 56 : s0);

    // ---- stage: x = 128 chunks (threads 0..127), mask = 40 chunks (128..167) ----
    if (t < 128) {
        const float* xsrc = x + (size_t)bc * 4096 + s0 * 64;
        __builtin_amdgcn_global_load_lds(
            (const __attribute__((address_space(1))) void*)(xsrc + t * 4),
            (__attribute__((address_space(3))) void*)(xs + (t & ~63) * 4),
            16, 0, 0);
    } else if (t < 168) {
        int i = t - 128;
        const uint32_t* msrc = mask + rg * 160;     // rows a..a+15 -> words a*10..
        __builtin_amdgcn_global_load_lds(
            (const __attribute__((address_space(1))) void*)(msrc + i * 4),
            (__attribute__((address_space(3))) void*)(ms + (i & ~63) * 4),
            16, 0, 0);
    }

    // ---- per-thread patterns for the 5 stores (computed during stage wait) ----
    int      xoffB[5][4];               // byte offsets within staged row
    int      rowB[5];                   // staged-row byte offset
    int      soffF[5];                  // output float offset within chunk
    int      midx[5];                   // mask word index
    uint32_t msh_[5];                   // shift within word
    #pragma unroll
    for (int ji = 0; ji < 5; ++ji) {
        int f  = t + 256 * ji;          // 0..1279 (block covers 1280 float4)
        int r0 = f / 80;                // local row 0..15
        int o4 = f - r0 * 80;           // float4 index in row
        int ow = o4 * 4;
        soffF[ji] = r0 * 320 + ow;
        msh_[ji]  = (uint32_t)((o4 & 7) * 4);
        midx[ji]  = r0 * 10 + (o4 >> 3);
        int oh = a + r0;
        int q = oh / 5, r = oh - q * 5;
        int ihrel = q + r - 2 - s0;
        ihrel = ihrel < 0 ? 0 : (ihrel > 7 ? 7 : ihrel);  // mask kills OOB
        rowB[ji] = ihrel * 256;
        #pragma unroll
        for (int k = 0; k < 4; ++k) {
            int o = ow + k;
            int qq = o / 5, rr = o - qq * 5;
            int iw = qq + rr - 2;
            iw = iw < 0 ? 0 : (iw > 63 ? 63 : iw);        // mask kills OOB
            xoffB[ji][k] = iw * 4;
        }
    }

    __syncthreads();                    // drains vmcnt, then barrier

    uint32_t mb[5];
    #pragma unroll
    for (int ji = 0; ji < 5; ++ji)
        mb[ji] = ms[midx[ji]] >> msh_[ji];

    float* ob = out + (size_t)b * 5120;       // linear 20 KB chunk
    const char* xsb = (const char*)xs;

    #pragma unroll
    for (int ji = 0; ji < 5; ++ji) {
        const char* xr = xsb + rowB[ji];
        uint32_t m = mb[ji];
        f32x4 o;
        o.x = (m & 1u) ? *(const float*)(xr + xoffB[ji][0]) * KEEP_SCALE : 0.0f;
        o.y = (m & 2u) ? *(const float*)(xr + xoffB[ji][1]) * KEEP_SCALE : 0.0f;
        o.z = (m & 4u) ? *(const float*)(xr + xoffB[ji][2]) * KEEP_SCALE : 0.0f;
        o.w = (m & 8u) ? *(const float*)(xr + xoffB[ji][3]) * KEEP_SCALE : 0.0f;
        *reinterpret_cast<f32x4*>(ob + soffF[ji]) = o;
    }
}

extern "C" void kernel_launch(void* const* d_in, const int* in_sizes, int n_in,
                              void* d_out, int out_size, void* d_ws, size_t ws_size,
                              hipStream_t stream) {
    const float* x  = (const float*)d_in[0];
    const float* rv = (const float*)d_in[1];
    float* out      = (float*)d_out;
    uint32_t* mask  = (uint32_t*)d_ws;      // 12.8 KB scratch

    hipLaunchKernelGGL(build_mask_kernel, dim3(13), dim3(256), 0, stream, rv, mask);

    dim3 block(256);
    dim3 grid(20480);                       // 1024 images x 20 chunks
    hipLaunchKernelGGL(expand_cps_dropout_kernel, grid, block, 0, stream,
                       x, mask, out);
}

// Round 11
// 87.038 us; speedup vs baseline: 1.0451x; 1.0451x over previous
//
#include <hip/hip_runtime.h>
#include <stdint.h>

// Expansion + checkerboard-preserving dropout.
// Phase 1: pack FINAL mask bits ((rand>0.25 | center) & in-bounds) into 3200 u32.
// Phase 2: fill-shaped main kernel: 512-thread blocks, each block = 32 contiguous
//          output rows (40 KB), flat LINEAR block->address mapping, grid = 10240
//          = exactly 10 residency rounds of 4 blocks/CU. Stage 12 x rows + 320
//          mask words via global_load_lds; 5 float4 stores per thread.

#define KEEP_SCALE (1.0f / 0.75f)

typedef float f32x4 __attribute__((ext_vector_type(4)));

__global__ __launch_bounds__(256) void build_mask_kernel(
    const float* __restrict__ rv,       // (320,320)
    uint32_t* __restrict__ mask)        // 3200 words, 10 per row
{
    int w = blockIdx.x * 256 + threadIdx.x;
    if (w >= 3200) return;
    int oh  = w / 10;
    int ow0 = (w - oh * 10) * 32;
    int qh = oh / 5, rh = oh - qh * 5;
    int ih = qh + rh - 2;
    bool hok = ((unsigned)ih < 64u);
    bool hc  = (rh == 2);
    const float* rp = rv + oh * 320 + ow0;
    uint32_t m = 0;
    #pragma unroll
    for (int b = 0; b < 32; ++b) {
        int ow = ow0 + b;
        int q = ow / 5, r = ow - q * 5;
        int iw = q + r - 2;
        bool keep = ((rp[b] > 0.25f) || (hc && (r == 2)))
                    && hok && ((unsigned)iw < 64u);
        m |= (uint32_t)keep << b;
    }
    mask[w] = m;
}

__global__ __launch_bounds__(512) void expand_cps_dropout_kernel(
    const float* __restrict__ x,        // (1024, 64, 64)
    const uint32_t* __restrict__ mask,  // 3200 words (bounds folded in)
    float* __restrict__ out)            // (1024, 320, 320)
{
    __shared__ __align__(16) float    xs[12 * 64];  // 3072 B: rows [s0, s0+12)
    __shared__ __align__(16) uint32_t ms[320];      // 1280 B: 32 rows x 10 words

    const int t  = threadIdx.x;         // 0..511
    const int b  = blockIdx.x;          // 0..10239, LINEAR over output
    const int bc = b / 10;              // image
    const int rg = b - bc * 10;         // 32-row chunk within image

    const int a = 32 * rg;              // first output row of this block
    int s0 = a / 5 - 2;                 // first staged source row
    s0 = s0 < 0 ? 0 : (s0 > 52 ? 52 : s0);

    // ---- stage: x = 192 chunks (t 0..191), mask = 80 chunks (t 192..271) ----
    if (t < 192) {
        const float* xsrc = x + (size_t)bc * 4096 + s0 * 64;
        __builtin_amdgcn_global_load_lds(
            (const __attribute__((address_space(1))) void*)(xsrc + t * 4),
            (__attribute__((address_space(3))) void*)(xs + (t & ~63) * 4),
            16, 0, 0);
    } else if (t < 272) {
        int i = t - 192;
        const uint32_t* msrc = mask + rg * 320;     // rows a..a+31 -> words a*10..
        __builtin_amdgcn_global_load_lds(
            (const __attribute__((address_space(1))) void*)(msrc + i * 4),
            (__attribute__((address_space(3))) void*)(ms + (i & ~63) * 4),
            16, 0, 0);
    }

    // ---- per-thread patterns for the 5 stores (computed during stage wait) ----
    int      xoffB[5][4];               // byte offsets within staged row
    int      rowB[5];                   // staged-row byte offset
    int      soffF[5];                  // output float offset within chunk
    int      midx[5];                   // mask word index
    uint32_t msh_[5];                   // shift within word
    #pragma unroll
    for (int ji = 0; ji < 5; ++ji) {
        int f  = t + 512 * ji;          // 0..2559 (block covers 2560 float4)
        int r0 = f / 80;                // local row 0..31
        int o4 = f - r0 * 80;           // float4 index in row
        int ow = o4 * 4;
        soffF[ji] = r0 * 320 + ow;
        msh_[ji]  = (uint32_t)((o4 & 7) * 4);
        midx[ji]  = r0 * 10 + (o4 >> 3);
        int oh = a + r0;
        int q = oh / 5, r = oh - q * 5;
        int ihrel = q + r - 2 - s0;
        ihrel = ihrel < 0 ? 0 : (ihrel > 11 ? 11 : ihrel);  // mask kills OOB
        rowB[ji] = ihrel * 256;
        #pragma unroll
        for (int k = 0; k < 4; ++k) {
            int o = ow + k;
            int qq = o / 5, rr = o - qq * 5;
            int iw = qq + rr - 2;
            iw = iw < 0 ? 0 : (iw > 63 ? 63 : iw);          // mask kills OOB
            xoffB[ji][k] = iw * 4;
        }
    }

    __syncthreads();                    // drains vmcnt, then barrier

    uint32_t mb[5];
    #pragma unroll
    for (int ji = 0; ji < 5; ++ji)
        mb[ji] = ms[midx[ji]] >> msh_[ji];

    float* ob = out + (size_t)b * 10240;      // linear 40 KB chunk
    const char* xsb = (const char*)xs;

    #pragma unroll
    for (int ji = 0; ji < 5; ++ji) {
        const char* xr = xsb + rowB[ji];
        uint32_t m = mb[ji];
        f32x4 o;
        o.x = (m & 1u) ? *(const float*)(xr + xoffB[ji][0]) * KEEP_SCALE : 0.0f;
        o.y = (m & 2u) ? *(const float*)(xr + xoffB[ji][1]) * KEEP_SCALE : 0.0f;
        o.z = (m & 4u) ? *(const float*)(xr + xoffB[ji][2]) * KEEP_SCALE : 0.0f;
        o.w = (m & 8u) ? *(const float*)(xr + xoffB[ji][3]) * KEEP_SCALE : 0.0f;
        *reinterpret_cast<f32x4*>(ob + soffF[ji]) = o;
    }
}

extern "C" void kernel_launch(void* const* d_in, const int* in_sizes, int n_in,
                              void* d_out, int out_size, void* d_ws, size_t ws_size,
                              hipStream_t stream) {
    const float* x  = (const float*)d_in[0];
    const float* rv = (const float*)d_in[1];
    float* out      = (float*)d_out;
    uint32_t* mask  = (uint32_t*)d_ws;      // 12.8 KB scratch

    hipLaunchKernelGGL(build_mask_kernel, dim3(13), dim3(256), 0, stream, rv, mask);

    dim3 block(512);
    dim3 grid(10240);                       // 1024 images x 10 chunks, linear
    hipLaunchKernelGGL(expand_cps_dropout_kernel, grid, block, 0, stream,
                       x, mask, out);
}

// Round 12
// 83.040 us; speedup vs baseline: 1.0955x; 1.0481x over previous
//
#include <hip/hip_runtime.h>
#include <stdint.h>

// Expansion + checkerboard-preserving dropout.
// Phase 1: ballot mask kernel — one thread per mask BIT (102400 bits); each wave
//          covers 64 consecutive bits of one row (320 = 5*64); lanes 0/32 store
//          the packed u32 words. Final mask = (rand>0.25 | center) & in-bounds.
// Phase 2: fill-shaped main kernel (unchanged from R11): 512-thread blocks, 32
//          contiguous output rows (40 KB) each, linear block->address mapping,
//          10240 blocks = 10 residency rounds. Stage 12 x rows + 320 mask words
//          via global_load_lds; 5 float4 stores per thread.

#define KEEP_SCALE (1.0f / 0.75f)

typedef float f32x4 __attribute__((ext_vector_type(4)));

__global__ __launch_bounds__(256) void build_mask_kernel(
    const float* __restrict__ rv,       // (320,320)
    uint32_t* __restrict__ mask)        // 3200 words, 10 per row
{
    const int g  = blockIdx.x * 256 + threadIdx.x;  // bit index, 0..102399
    const int oh = g / 320;
    const int ow = g - oh * 320;

    int qh = oh / 5, rh = oh - qh * 5;
    int ih = qh + rh - 2;
    int q  = ow / 5, r  = ow - q * 5;
    int iw = q + r - 2;

    float v = rv[g];                    // coalesced: 64 consecutive floats/wave
    bool keep = ((v > 0.25f) || (rh == 2 && r == 2))
                && ((unsigned)ih < 64u) && ((unsigned)iw < 64u);

    unsigned long long bal = __ballot(keep);
    int lane = threadIdx.x & 63;
    if (lane == 0)
        mask[g >> 5] = (uint32_t)bal;
    else if (lane == 32)
        mask[g >> 5] = (uint32_t)(bal >> 32);
}

__global__ __launch_bounds__(512) void expand_cps_dropout_kernel(
    const float* __restrict__ x,        // (1024, 64, 64)
    const uint32_t* __restrict__ mask,  // 3200 words (bounds folded in)
    float* __restrict__ out)            // (1024, 320, 320)
{
    __shared__ __align__(16) float    xs[12 * 64];  // 3072 B: rows [s0, s0+12)
    __shared__ __align__(16) uint32_t ms[320];      // 1280 B: 32 rows x 10 words

    const int t  = threadIdx.x;         // 0..511
    const int b  = blockIdx.x;          // 0..10239, LINEAR over output
    const int bc = b / 10;              // image
    const int rg = b - bc * 10;         // 32-row chunk within image

    const int a = 32 * rg;              // first output row of this block
    int s0 = a / 5 - 2;                 // first staged source row
    s0 = s0 < 0 ? 0 : (s0 > 52 ? 52 : s0);

    // ---- stage: x = 192 chunks (t 0..191), mask = 80 chunks (t 192..271) ----
    if (t < 192) {
        const float* xsrc = x + (size_t)bc * 4096 + s0 * 64;
        __builtin_amdgcn_global_load_lds(
            (const __attribute__((address_space(1))) void*)(xsrc + t * 4),
            (__attribute__((address_space(3))) void*)(xs + (t & ~63) * 4),
            16, 0, 0);
    } else if (t < 272) {
        int i = t - 192;
        const uint32_t* msrc = mask + rg * 320;     // rows a..a+31 -> words a*10..
        __builtin_amdgcn_global_load_lds(
            (const __attribute__((address_space(1))) void*)(msrc + i * 4),
            (__attribute__((address_space(3))) void*)(ms + (i & ~63) * 4),
            16, 0, 0);
    }

    // ---- per-thread patterns for the 5 stores (computed during stage wait) ----
    int      xoffB[5][4];               // byte offsets within staged row
    int      rowB[5];                   // staged-row byte offset
    int      soffF[5];                  // output float offset within chunk
    int      midx[5];                   // mask word index
    uint32_t msh_[5];                   // shift within word
    #pragma unroll
    for (int ji = 0; ji < 5; ++ji) {
        int f  = t + 512 * ji;          // 0..2559 (block covers 2560 float4)
        int r0 = f / 80;                // local row 0..31
        int o4 = f - r0 * 80;           // float4 index in row
        int ow = o4 * 4;
        soffF[ji] = r0 * 320 + ow;
        msh_[ji]  = (uint32_t)((o4 & 7) * 4);
        midx[ji]  = r0 * 10 + (o4 >> 3);
        int oh = a + r0;
        int q = oh / 5, r = oh - q * 5;
        int ihrel = q + r - 2 - s0;
        ihrel = ihrel < 0 ? 0 : (ihrel > 11 ? 11 : ihrel);  // mask kills OOB
        rowB[ji] = ihrel * 256;
        #pragma unroll
        for (int k = 0; k < 4; ++k) {
            int o = ow + k;
            int qq = o / 5, rr = o - qq * 5;
            int iw = qq + rr - 2;
            iw = iw < 0 ? 0 : (iw > 63 ? 63 : iw);          // mask kills OOB
            xoffB[ji][k] = iw * 4;
        }
    }

    __syncthreads();                    // drains vmcnt, then barrier

    uint32_t mb[5];
    #pragma unroll
    for (int ji = 0; ji < 5; ++ji)
        mb[ji] = ms[midx[ji]] >> msh_[ji];

    float* ob = out + (size_t)b * 10240;      // linear 40 KB chunk
    const char* xsb = (const char*)xs;

    #pragma unroll
    for (int ji = 0; ji < 5; ++ji) {
        const char* xr = xsb + rowB[ji];
        uint32_t m = mb[ji];
        f32x4 o;
        o.x = (m & 1u) ? *(const float*)(xr + xoffB[ji][0]) * KEEP_SCALE : 0.0f;
        o.y = (m & 2u) ? *(const float*)(xr + xoffB[ji][1]) * KEEP_SCALE : 0.0f;
        o.z = (m & 4u) ? *(const float*)(xr + xoffB[ji][2]) * KEEP_SCALE : 0.0f;
        o.w = (m & 8u) ? *(const float*)(xr + xoffB[ji][3]) * KEEP_SCALE : 0.0f;
        *reinterpret_cast<f32x4*>(ob + soffF[ji]) = o;
    }
}

extern "C" void kernel_launch(void* const* d_in, const int* in_sizes, int n_in,
                              void* d_out, int out_size, void* d_ws, size_t ws_size,
                              hipStream_t stream) {
    const float* x  = (const float*)d_in[0];
    const float* rv = (const float*)d_in[1];
    float* out      = (float*)d_out;
    uint32_t* mask  = (uint32_t*)d_ws;      // 12.8 KB scratch

    hipLaunchKernelGGL(build_mask_kernel, dim3(400), dim3(256), 0, stream, rv, mask);

    dim3 block(512);
    dim3 grid(10240);                       // 1024 images x 10 chunks, linear
    hipLaunchKernelGGL(expand_cps_dropout_kernel, grid, block, 0, stream,
                       x, mask, out);
}